// Round 4
// baseline (820.446 us; speedup 1.0000x reference)
//
#include <hip/hip_runtime.h>

#define NGRAPH 256
#define FIN 64
#define HID 32
#define NB_SHIFT 7            // 128 nodes per bucket
#define NB_NODES 128
#define KMAX 1024
#define EPB 2048              // edges per partition block
#define EPT 8                 // edges per thread (256 threads)

// ---------- node GEMMs ----------
__global__ __launch_bounds__(256) void node_lin64(
    const float* __restrict__ x, const float* __restrict__ Wrel,
    const float* __restrict__ Wroot, const float* __restrict__ bias,
    float* __restrict__ A, float* __restrict__ B, int N)
{
    __shared__ float sWr[FIN * HID];
    __shared__ float sWo[FIN * HID];
    __shared__ float sb[HID];
    __shared__ float sx[8 * FIN];
    int tid = threadIdx.x;
    for (int i = tid; i < FIN * HID; i += 256) { sWr[i] = Wrel[i]; sWo[i] = Wroot[i]; }
    if (tid < HID) sb[tid] = bias[tid];
    int base = blockIdx.x * 8;
    for (int i = tid; i < 8 * FIN; i += 256) {
        int n = base + i / FIN;
        sx[i] = (n < N) ? x[(size_t)n * FIN + (i % FIN)] : 0.f;
    }
    __syncthreads();
    int nl = tid >> 5, f = tid & 31, n = base + nl;
    if (n >= N) return;
    float ar = 0.f, ao = 0.f;
    #pragma unroll
    for (int k = 0; k < FIN; ++k) {
        float xv = sx[nl * FIN + k];
        ar = fmaf(xv, sWr[k * HID + f], ar);
        ao = fmaf(xv, sWo[k * HID + f], ao);
    }
    A[(size_t)n * HID + f] = ar;
    B[(size_t)n * HID + f] = ao + sb[f];
}

__global__ __launch_bounds__(256) void node_lin32(
    const float* __restrict__ Hpre, const float* __restrict__ Wrel,
    const float* __restrict__ Wroot, const float* __restrict__ bias,
    float* __restrict__ A, float* __restrict__ C, int N)
{
    __shared__ float sWr[HID * HID];
    __shared__ float sWo[HID * HID];
    __shared__ float sb[HID];
    __shared__ float sh[8 * HID];
    int tid = threadIdx.x;
    for (int i = tid; i < HID * HID; i += 256) { sWr[i] = Wrel[i]; sWo[i] = Wroot[i]; }
    if (tid < HID) sb[tid] = bias[tid];
    int base = blockIdx.x * 8;
    for (int i = tid; i < 8 * HID; i += 256) {
        int n = base + i / HID;
        float v = (n < N) ? Hpre[(size_t)n * HID + (i % HID)] : 0.f;
        sh[i] = v > 0.f ? v : 0.f;
    }
    __syncthreads();
    int nl = tid >> 5, f = tid & 31, n = base + nl;
    if (n >= N) return;
    float ar = 0.f, ao = 0.f;
    #pragma unroll
    for (int k = 0; k < HID; ++k) {
        float hv = sh[nl * HID + k];
        ar = fmaf(hv, sWr[k * HID + f], ar);
        ao = fmaf(hv, sWo[k * HID + f], ao);
    }
    A[(size_t)n * HID + f] = ar;
    C[(size_t)n * HID + f] = ao + sb[f];
}

// ---------- deterministic two-level partition build (no global atomics) ----------

// per-(edge-block, bucket) histogram via LDS; write column blk of cbb
__global__ __launch_bounds__(256) void bucket_hist(
    const int* __restrict__ dst, int* __restrict__ cbb, int E, int K, int NBLK)
{
    __shared__ int h[KMAX];
    int tid = threadIdx.x;
    for (int i = tid; i < K; i += 256) h[i] = 0;
    __syncthreads();
    int e0 = blockIdx.x * EPB + tid * 8;
    if (e0 + 7 < E) {
        int4 d0 = *reinterpret_cast<const int4*>(dst + e0);
        int4 d1 = *reinterpret_cast<const int4*>(dst + e0 + 4);
        atomicAdd(&h[d0.x >> NB_SHIFT], 1); atomicAdd(&h[d0.y >> NB_SHIFT], 1);
        atomicAdd(&h[d0.z >> NB_SHIFT], 1); atomicAdd(&h[d0.w >> NB_SHIFT], 1);
        atomicAdd(&h[d1.x >> NB_SHIFT], 1); atomicAdd(&h[d1.y >> NB_SHIFT], 1);
        atomicAdd(&h[d1.z >> NB_SHIFT], 1); atomicAdd(&h[d1.w >> NB_SHIFT], 1);
    } else {
        for (int e = e0; e < E && e < e0 + 8; ++e)
            atomicAdd(&h[dst[e] >> NB_SHIFT], 1);
    }
    __syncthreads();
    for (int i = tid; i < K; i += 256)
        cbb[(size_t)i * NBLK + blockIdx.x] = h[i];
}

// in-place exclusive scan of each bucket row of cbb; bucket total -> btot
__global__ __launch_bounds__(256) void bucket_scan(
    int* __restrict__ cbb, int* __restrict__ btot, int NBLK)
{
    __shared__ int sc[256];
    size_t row = (size_t)blockIdx.x * NBLK;
    int t = threadIdx.x;
    int base = t * 4;
    int v[4]; int s = 0;
    #pragma unroll
    for (int j = 0; j < 4; ++j) { v[j] = (base + j < NBLK) ? cbb[row + base + j] : 0; s += v[j]; }
    sc[t] = s;
    __syncthreads();
    int acc = s;
    for (int off = 1; off < 256; off <<= 1) {
        int add = (t >= off) ? sc[t - off] : 0;
        __syncthreads();
        acc += add;
        sc[t] = acc;
        __syncthreads();
    }
    int run = acc - s;
    #pragma unroll
    for (int j = 0; j < 4; ++j) {
        if (base + j < NBLK) cbb[row + base + j] = run;
        run += v[j];
    }
    if (t == 255) btot[blockIdx.x] = acc;
}

// single-block exclusive scan of bucket totals -> bbase[0..K], bbase[K]=E
__global__ __launch_bounds__(256) void btot_scan(
    const int* __restrict__ btot, int* __restrict__ bbase, int K)
{
    __shared__ int sc[256];
    int t = threadIdx.x;
    int base = t * 4;
    int v[4]; int s = 0;
    #pragma unroll
    for (int j = 0; j < 4; ++j) { v[j] = (base + j < K) ? btot[base + j] : 0; s += v[j]; }
    sc[t] = s;
    __syncthreads();
    int acc = s;
    for (int off = 1; off < 256; off <<= 1) {
        int add = (t >= off) ? sc[t - off] : 0;
        __syncthreads();
        acc += add;
        sc[t] = acc;
        __syncthreads();
    }
    int run = acc - s;
    #pragma unroll
    for (int j = 0; j < 4; ++j) {
        if (base + j < K) bbase[base + j] = run;
        run += v[j];
    }
    if (t == 255) bbase[K] = acc;
}

// partition: edges -> bucket-grouped staging, offsets fully precomputed
__global__ __launch_bounds__(256) void partB(
    const int* __restrict__ src, const int* __restrict__ dst,
    const float* __restrict__ ew, const int* __restrict__ cbb,
    const int* __restrict__ bbase, int4* __restrict__ stg,
    int E, int K, int NBLK)
{
    __shared__ int4 pay[EPB];
    __shared__ int h[KMAX];     // hist, then LDS cursor
    __shared__ int lofs[KMAX];
    __shared__ int gb[KMAX];
    __shared__ int sc[256];
    int tid = threadIdx.x;
    for (int i = tid; i < K; i += 256) h[i] = 0;
    __syncthreads();

    int base = blockIdx.x * EPB;
    int es[EPT], ds[EPT]; float wsr[EPT];
    #pragma unroll
    for (int k = 0; k < EPT; ++k) {
        int e = base + k * 256 + tid;
        if (e < E) {
            es[k] = src[e]; ds[k] = dst[e]; wsr[k] = ew[e];
            atomicAdd(&h[ds[k] >> NB_SHIFT], 1);
        } else ds[k] = -1;
    }
    __syncthreads();

    // block-scan hist over K buckets
    int b0 = tid * 4;
    int v[4], s = 0;
    #pragma unroll
    for (int j = 0; j < 4; ++j) { int b = b0 + j; v[j] = (b < K) ? h[b] : 0; s += v[j]; }
    sc[tid] = s;
    __syncthreads();
    int acc = s;
    for (int off = 1; off < 256; off <<= 1) {
        int add = (tid >= off) ? sc[tid - off] : 0;
        __syncthreads();
        acc += add;
        sc[tid] = acc;
        __syncthreads();
    }
    int run = acc - s;
    #pragma unroll
    for (int j = 0; j < 4; ++j) {
        int b = b0 + j;
        if (b < K) lofs[b] = run;
        run += v[j];
    }
    __syncthreads();

    // deterministic global bases; convert h[] into LDS scatter cursors
    for (int b = tid; b < K; b += 256) {
        gb[b] = bbase[b] + cbb[(size_t)b * NBLK + blockIdx.x];
        h[b] = lofs[b];
    }
    __syncthreads();

    #pragma unroll
    for (int k = 0; k < EPT; ++k) {
        if (ds[k] >= 0) {
            int b = ds[k] >> NB_SHIFT;
            int slot = atomicAdd(&h[b], 1);
            pay[slot] = make_int4(es[k], __float_as_int(wsr[k]), ds[k],
                                  gb[b] + slot - lofs[b]);
        }
    }
    __syncthreads();

    int tot = E - base; if (tot > EPB) tot = EPB;
    for (int i = tid; i < tot; i += 256) {
        int4 p = pay[i];
        stg[p.w] = make_int4(p.x, p.y, p.z, 0);
    }
}

// ---------- fused aggregation: per bucket, LDS accumulator ----------
__global__ __launch_bounds__(256) void agg_bucket(
    const int4* __restrict__ stg, const int* __restrict__ bbase,
    const float* __restrict__ A, float* __restrict__ out, int N)
{
    __shared__ float acc[NB_NODES * HID];   // 16 KB
    int b = blockIdx.x;
    int n0 = b << NB_SHIFT;
    int nTop = n0 + NB_NODES; if (nTop > N) nTop = N;
    int nElem = (nTop - n0) * HID;
    int tid = threadIdx.x;
    for (int i = tid; i < nElem; i += 256) acc[i] = out[(size_t)n0 * HID + i];
    __syncthreads();
    int lo = bbase[b], hi = bbase[b + 1];
    int g = tid >> 5, f = tid & 31;   // 8 edge-slots x 32 features
    #pragma unroll 2
    for (int e = lo + g; e < hi; e += 8) {
        int4 v = stg[e];
        float a = A[((size_t)v.x << 5) + f];
        atomicAdd(&acc[((v.z - n0) << 5) + f], a * __int_as_float(v.y));
    }
    __syncthreads();
    for (int i = tid; i < nElem; i += 256) out[(size_t)n0 * HID + i] = acc[i];
}

// ---------- pool + MLP ----------
__global__ __launch_bounds__(256) void pool_kernel(
    const float* __restrict__ C, const int* __restrict__ batch,
    float* __restrict__ sums, float* __restrict__ cnts, int N)
{
    int f = threadIdx.x & 31, g = threadIdx.x >> 5;
    int n0 = blockIdx.x * 256 + g * 32;
    if (n0 >= N) return;
    int n1 = n0 + 32; if (n1 > N) n1 = N;
    int cur = batch[n0];
    float acc = 0.f, cnt = 0.f;
    for (int n = n0; n < n1; ++n) {
        int b = batch[n];
        if (b != cur) {
            atomicAdd(&sums[cur * HID + f], acc);
            if (f == 0) atomicAdd(&cnts[cur], cnt);
            acc = 0.f; cnt = 0.f; cur = b;
        }
        float v = C[(size_t)n * HID + f];
        acc += v > 0.f ? v : 0.f;
        cnt += 1.f;
    }
    atomicAdd(&sums[cur * HID + f], acc);
    if (f == 0) atomicAdd(&cnts[cur], cnt);
}

__global__ __launch_bounds__(256) void mlp_kernel(
    const float* __restrict__ sums, const float* __restrict__ cnts,
    const float* __restrict__ W1, const float* __restrict__ b1,
    const float* __restrict__ W2, const float* __restrict__ b2,
    const float* __restrict__ W3, const float* __restrict__ b3,
    float* __restrict__ out)
{
    __shared__ float sW1[32 * 32], sb1[32], sW2[32 * 16], sb2[16], sW3[16], sb3;
    int tid = threadIdx.x;
    for (int i = tid; i < 32 * 32; i += 256) sW1[i] = W1[i];
    for (int i = tid; i < 32 * 16; i += 256) sW2[i] = W2[i];
    if (tid < 32) sb1[tid] = b1[tid];
    if (tid < 16) { sb2[tid] = b2[tid]; sW3[tid] = W3[tid]; }
    if (tid == 0) sb3 = b3[0];
    __syncthreads();
    int gi = tid;
    float c = cnts[gi]; c = c > 1.f ? c : 1.f;
    float inv = 1.f / c;
    float gvec[32];
    #pragma unroll
    for (int i = 0; i < 32; ++i) gvec[i] = sums[gi * 32 + i] * inv;
    float h1[32];
    #pragma unroll
    for (int j = 0; j < 32; ++j) {
        float a = sb1[j];
        #pragma unroll
        for (int k = 0; k < 32; ++k) a = fmaf(gvec[k], sW1[k * 32 + j], a);
        h1[j] = a > 0.f ? a : 0.f;
    }
    float o = sb3;
    #pragma unroll
    for (int j = 0; j < 16; ++j) {
        float a = sb2[j];
        #pragma unroll
        for (int k = 0; k < 32; ++k) a = fmaf(h1[k], sW2[k * 16 + j], a);
        a = a > 0.f ? a : 0.f;
        o = fmaf(a, sW3[j], o);
    }
    out[gi] = o;
}

extern "C" void kernel_launch(void* const* d_in, const int* in_sizes, int n_in,
                              void* d_out, int out_size, void* d_ws, size_t ws_size,
                              hipStream_t stream) {
    const float* x     = (const float*)d_in[0];
    const int*   ei    = (const int*)d_in[1];
    const float* ew    = (const float*)d_in[2];
    const int*   batch = (const int*)d_in[3];
    const float* c1rw  = (const float*)d_in[4];
    const float* c1rb  = (const float*)d_in[5];
    const float* c1ow  = (const float*)d_in[6];
    const float* c2rw  = (const float*)d_in[7];
    const float* c2rb  = (const float*)d_in[8];
    const float* c2ow  = (const float*)d_in[9];
    const float* l1w   = (const float*)d_in[10];
    const float* l1b   = (const float*)d_in[11];
    const float* l2w   = (const float*)d_in[12];
    const float* l2b   = (const float*)d_in[13];
    const float* lw    = (const float*)d_in[14];
    const float* lb    = (const float*)d_in[15];

    int N = in_sizes[0] / FIN;      // 100000
    int E = in_sizes[2];            // 1600000
    const int* src = ei;
    const int* dst = ei + E;
    int K    = (N + NB_NODES - 1) >> NB_SHIFT;   // 782 buckets
    int NBLK = (E + EPB - 1) / EPB;              // 782 edge blocks

    // ---- workspace layout ----
    char* ws = (char*)d_ws;
    size_t off = 0;
    auto alloc = [&](size_t nbytes) { void* p = ws + off; off += (nbytes + 255) & ~size_t(255); return p; };
    float* A     = (float*)alloc((size_t)N * HID * 4);   // cbb aliases front of A
    float* BC    = (float*)alloc((size_t)N * HID * 4);   // conv1 out, then conv2 out
    int4*  stg   = (int4*) alloc((size_t)E * 16);
    int*   btot  = (int*)  alloc((size_t)KMAX * 4);
    int*   bbase = (int*)  alloc((size_t)(KMAX + 1) * 4);
    float* sums  = (float*)alloc(NGRAPH * HID * 4);
    float* cnts  = (float*)alloc(NGRAPH * 4);
    int*   cbb   = (int*)A;   // K*NBLK ints = 2.45 MB << 12.8 MB; dead before node_lin64

    hipMemsetAsync(sums, 0, (NGRAPH * HID + NGRAPH) * 4, stream);

    int nb_node = (N + 7) / 8;

    // partition build (no global atomics)
    bucket_hist<<<NBLK, 256, 0, stream>>>(dst, cbb, E, K, NBLK);
    bucket_scan<<<K, 256, 0, stream>>>(cbb, btot, NBLK);
    btot_scan<<<1, 256, 0, stream>>>(btot, bbase, K);
    partB<<<NBLK, 256, 0, stream>>>(src, dst, ew, cbb, bbase, stg, E, K, NBLK);

    // conv1
    node_lin64<<<nb_node, 256, 0, stream>>>(x, c1rw, c1ow, c1rb, A, BC, N);
    agg_bucket<<<K, 256, 0, stream>>>(stg, bbase, A, BC, N);
    // conv2 (relu fused into node_lin32 load; C aliases B safely: block-local rows)
    node_lin32<<<nb_node, 256, 0, stream>>>(BC, c2rw, c2ow, c2rb, A, BC, N);
    agg_bucket<<<K, 256, 0, stream>>>(stg, bbase, A, BC, N);
    // pool + MLP
    pool_kernel<<<(N + 255) / 256, 256, 0, stream>>>(BC, batch, sums, cnts, N);
    mlp_kernel<<<1, 256, 0, stream>>>(sums, cnts, l1w, l1b, l2w, l2b, lw, lb,
                                      (float*)d_out);
}

// Round 5
// 283.872 us; speedup vs baseline: 2.8902x; 2.8902x over previous
//
#include <hip/hip_runtime.h>

#define NGRAPH 256
#define FIN 64
#define HID 32
#define NB_SHIFT 7            // 128 nodes per bucket
#define NB_NODES 128
#define KMAX 1024
#define EPB 2048              // edges per partition block
#define EPT 8                 // edges per thread (256 threads)

// ---------- node GEMMs ----------
__global__ __launch_bounds__(256) void node_lin64(
    const float* __restrict__ x, const float* __restrict__ Wrel,
    const float* __restrict__ Wroot, const float* __restrict__ bias,
    float* __restrict__ A, float* __restrict__ B, int N)
{
    __shared__ float sWr[FIN * HID];
    __shared__ float sWo[FIN * HID];
    __shared__ float sb[HID];
    __shared__ float sx[8 * FIN];
    int tid = threadIdx.x;
    for (int i = tid; i < FIN * HID; i += 256) { sWr[i] = Wrel[i]; sWo[i] = Wroot[i]; }
    if (tid < HID) sb[tid] = bias[tid];
    int base = blockIdx.x * 8;
    for (int i = tid; i < 8 * FIN; i += 256) {
        int n = base + i / FIN;
        sx[i] = (n < N) ? x[(size_t)n * FIN + (i % FIN)] : 0.f;
    }
    __syncthreads();
    int nl = tid >> 5, f = tid & 31, n = base + nl;
    if (n >= N) return;
    float ar = 0.f, ao = 0.f;
    #pragma unroll
    for (int k = 0; k < FIN; ++k) {
        float xv = sx[nl * FIN + k];
        ar = fmaf(xv, sWr[k * HID + f], ar);
        ao = fmaf(xv, sWo[k * HID + f], ao);
    }
    A[(size_t)n * HID + f] = ar;
    B[(size_t)n * HID + f] = ao + sb[f];
}

__global__ __launch_bounds__(256) void node_lin32(
    const float* __restrict__ Hpre, const float* __restrict__ Wrel,
    const float* __restrict__ Wroot, const float* __restrict__ bias,
    float* __restrict__ A, float* __restrict__ C, int N)
{
    __shared__ float sWr[HID * HID];
    __shared__ float sWo[HID * HID];
    __shared__ float sb[HID];
    __shared__ float sh[8 * HID];
    int tid = threadIdx.x;
    for (int i = tid; i < HID * HID; i += 256) { sWr[i] = Wrel[i]; sWo[i] = Wroot[i]; }
    if (tid < HID) sb[tid] = bias[tid];
    int base = blockIdx.x * 8;
    for (int i = tid; i < 8 * HID; i += 256) {
        int n = base + i / HID;
        float v = (n < N) ? Hpre[(size_t)n * HID + (i % HID)] : 0.f;
        sh[i] = v > 0.f ? v : 0.f;
    }
    __syncthreads();
    int nl = tid >> 5, f = tid & 31, n = base + nl;
    if (n >= N) return;
    float ar = 0.f, ao = 0.f;
    #pragma unroll
    for (int k = 0; k < HID; ++k) {
        float hv = sh[nl * HID + k];
        ar = fmaf(hv, sWr[k * HID + f], ar);
        ao = fmaf(hv, sWo[k * HID + f], ao);
    }
    A[(size_t)n * HID + f] = ar;
    C[(size_t)n * HID + f] = ao + sb[f];
}

// ---------- deterministic two-level partition build (no global atomics) ----------

// per-(edge-block, bucket) histogram via LDS; write column blk of cbb
__global__ __launch_bounds__(256) void bucket_hist(
    const int* __restrict__ dst, int* __restrict__ cbb, int E, int K, int NBLK)
{
    __shared__ int h[KMAX];
    int tid = threadIdx.x;
    for (int i = tid; i < K; i += 256) h[i] = 0;
    __syncthreads();
    int e0 = blockIdx.x * EPB + tid * 8;
    if (e0 + 7 < E) {
        int4 d0 = *reinterpret_cast<const int4*>(dst + e0);
        int4 d1 = *reinterpret_cast<const int4*>(dst + e0 + 4);
        atomicAdd(&h[d0.x >> NB_SHIFT], 1); atomicAdd(&h[d0.y >> NB_SHIFT], 1);
        atomicAdd(&h[d0.z >> NB_SHIFT], 1); atomicAdd(&h[d0.w >> NB_SHIFT], 1);
        atomicAdd(&h[d1.x >> NB_SHIFT], 1); atomicAdd(&h[d1.y >> NB_SHIFT], 1);
        atomicAdd(&h[d1.z >> NB_SHIFT], 1); atomicAdd(&h[d1.w >> NB_SHIFT], 1);
    } else {
        for (int e = e0; e < E && e < e0 + 8; ++e)
            atomicAdd(&h[dst[e] >> NB_SHIFT], 1);
    }
    __syncthreads();
    for (int i = tid; i < K; i += 256)
        cbb[(size_t)i * NBLK + blockIdx.x] = h[i];
}

// in-place exclusive scan of each bucket row of cbb; bucket total -> btot
__global__ __launch_bounds__(256) void bucket_scan(
    int* __restrict__ cbb, int* __restrict__ btot, int NBLK)
{
    __shared__ int sc[256];
    size_t row = (size_t)blockIdx.x * NBLK;
    int t = threadIdx.x;
    int base = t * 4;
    int v[4]; int s = 0;
    #pragma unroll
    for (int j = 0; j < 4; ++j) { v[j] = (base + j < NBLK) ? cbb[row + base + j] : 0; s += v[j]; }
    sc[t] = s;
    __syncthreads();
    int acc = s;
    for (int off = 1; off < 256; off <<= 1) {
        int add = (t >= off) ? sc[t - off] : 0;
        __syncthreads();
        acc += add;
        sc[t] = acc;
        __syncthreads();
    }
    int run = acc - s;
    #pragma unroll
    for (int j = 0; j < 4; ++j) {
        if (base + j < NBLK) cbb[row + base + j] = run;
        run += v[j];
    }
    if (t == 255) btot[blockIdx.x] = acc;
}

// single-block exclusive scan of bucket totals -> bbase[0..K], bbase[K]=E
__global__ __launch_bounds__(256) void btot_scan(
    const int* __restrict__ btot, int* __restrict__ bbase, int K)
{
    __shared__ int sc[256];
    int t = threadIdx.x;
    int base = t * 4;
    int v[4]; int s = 0;
    #pragma unroll
    for (int j = 0; j < 4; ++j) { v[j] = (base + j < K) ? btot[base + j] : 0; s += v[j]; }
    sc[t] = s;
    __syncthreads();
    int acc = s;
    for (int off = 1; off < 256; off <<= 1) {
        int add = (t >= off) ? sc[t - off] : 0;
        __syncthreads();
        acc += add;
        sc[t] = acc;
        __syncthreads();
    }
    int run = acc - s;
    #pragma unroll
    for (int j = 0; j < 4; ++j) {
        if (base + j < K) bbase[base + j] = run;
        run += v[j];
    }
    if (t == 255) bbase[K] = acc;
}

// partition: edges -> bucket-grouped staging, offsets fully precomputed
__global__ __launch_bounds__(256) void partB(
    const int* __restrict__ src, const int* __restrict__ dst,
    const float* __restrict__ ew, const int* __restrict__ cbb,
    const int* __restrict__ bbase, int2* __restrict__ stg8,
    int* __restrict__ stgd, int E, int K, int NBLK)
{
    __shared__ int4 pay[EPB];
    __shared__ int h[KMAX];     // hist, then LDS cursor
    __shared__ int lofs[KMAX];
    __shared__ int gb[KMAX];
    __shared__ int sc[256];
    int tid = threadIdx.x;
    for (int i = tid; i < K; i += 256) h[i] = 0;
    __syncthreads();

    int base = blockIdx.x * EPB;
    int es[EPT], ds[EPT]; float wsr[EPT];
    #pragma unroll
    for (int k = 0; k < EPT; ++k) {
        int e = base + k * 256 + tid;
        if (e < E) {
            es[k] = src[e]; ds[k] = dst[e]; wsr[k] = ew[e];
            atomicAdd(&h[ds[k] >> NB_SHIFT], 1);
        } else ds[k] = -1;
    }
    __syncthreads();

    int b0 = tid * 4;
    int v[4], s = 0;
    #pragma unroll
    for (int j = 0; j < 4; ++j) { int b = b0 + j; v[j] = (b < K) ? h[b] : 0; s += v[j]; }
    sc[tid] = s;
    __syncthreads();
    int acc = s;
    for (int off = 1; off < 256; off <<= 1) {
        int add = (tid >= off) ? sc[tid - off] : 0;
        __syncthreads();
        acc += add;
        sc[tid] = acc;
        __syncthreads();
    }
    int run = acc - s;
    #pragma unroll
    for (int j = 0; j < 4; ++j) {
        int b = b0 + j;
        if (b < K) lofs[b] = run;
        run += v[j];
    }
    __syncthreads();

    for (int b = tid; b < K; b += 256) {
        gb[b] = bbase[b] + cbb[(size_t)b * NBLK + blockIdx.x];
        h[b] = lofs[b];
    }
    __syncthreads();

    #pragma unroll
    for (int k = 0; k < EPT; ++k) {
        if (ds[k] >= 0) {
            int b = ds[k] >> NB_SHIFT;
            int slot = atomicAdd(&h[b], 1);
            pay[slot] = make_int4(es[k], __float_as_int(wsr[k]), ds[k],
                                  gb[b] + slot - lofs[b]);
        }
    }
    __syncthreads();

    int tot = E - base; if (tot > EPB) tot = EPB;
    for (int i = tid; i < tot; i += 256) {
        int4 p = pay[i];
        stg8[p.w] = make_int2(p.x, p.y);
        stgd[p.w] = p.z;
    }
}

// per bucket: counting-sort edges by dst node in LDS, emit rowptr + node-sorted perm
__global__ __launch_bounds__(256) void partC2(
    const int2* __restrict__ stg8, const int* __restrict__ stgd,
    const int* __restrict__ bbase, int* __restrict__ rowptr,
    int2* __restrict__ perm, int N, int K)
{
    __shared__ int hcnt[NB_NODES];
    __shared__ int hofs[NB_NODES];
    int b = blockIdx.x;
    int n0 = b << NB_SHIFT;
    int nTop = n0 + NB_NODES; if (nTop > N) nTop = N;
    int nloc = nTop - n0;
    int tid = threadIdx.x;
    if (tid < nloc) hcnt[tid] = 0;
    __syncthreads();
    int lo = bbase[b], hi = bbase[b + 1];
    for (int e = lo + tid; e < hi; e += 256)
        atomicAdd(&hcnt[stgd[e] - n0], 1);
    __syncthreads();
    if (tid == 0) {
        int run = 0;
        for (int i = 0; i < nloc; ++i) { hofs[i] = run; run += hcnt[i]; }
    }
    __syncthreads();
    if (tid < nloc) {
        rowptr[n0 + tid] = lo + hofs[tid];
        hcnt[tid] = hofs[tid];          // reuse as cursor
    }
    if (b == K - 1 && tid == 0) rowptr[N] = hi;
    __syncthreads();
    for (int e = lo + tid; e < hi; e += 256) {
        int2 p = stg8[e];
        int pos = lo + atomicAdd(&hcnt[stgd[e] - n0], 1);
        perm[pos] = p;
    }
}

// ---------- gather-side aggregation ----------
// 64 lanes per node: two halves of edge list, xor-combine, 2-way unroll
__global__ __launch_bounds__(256) void csr_agg(
    const int* __restrict__ rowptr, const int2* __restrict__ perm,
    const float* __restrict__ A, float* __restrict__ out, int N)
{
    int gid = blockIdx.x * 256 + threadIdx.x;
    int n = gid >> 6;
    if (n >= N) return;
    int half = (threadIdx.x >> 5) & 1;
    int f = threadIdx.x & 31;
    int e0 = rowptr[n], e1 = rowptr[n + 1];
    float a0 = 0.f, a1 = 0.f;
    int e = e0 + half;
    for (; e + 2 < e1; e += 4) {
        int2 p0 = perm[e];
        int2 p1 = perm[e + 2];
        a0 = fmaf(A[(size_t)p0.x * HID + f], __int_as_float(p0.y), a0);
        a1 = fmaf(A[(size_t)p1.x * HID + f], __int_as_float(p1.y), a1);
    }
    for (; e < e1; e += 2) {
        int2 p = perm[e];
        a0 = fmaf(A[(size_t)p.x * HID + f], __int_as_float(p.y), a0);
    }
    float acc = a0 + a1;
    acc += __shfl_xor(acc, 32, 64);
    if (half == 0) out[(size_t)n * HID + f] += acc;
}

// ---------- pool + MLP ----------
__global__ __launch_bounds__(256) void pool_kernel(
    const float* __restrict__ C, const int* __restrict__ batch,
    float* __restrict__ sums, float* __restrict__ cnts, int N)
{
    int f = threadIdx.x & 31, g = threadIdx.x >> 5;
    int n0 = blockIdx.x * 256 + g * 32;
    if (n0 >= N) return;
    int n1 = n0 + 32; if (n1 > N) n1 = N;
    int cur = batch[n0];
    float acc = 0.f, cnt = 0.f;
    for (int n = n0; n < n1; ++n) {
        int b = batch[n];
        if (b != cur) {
            atomicAdd(&sums[cur * HID + f], acc);
            if (f == 0) atomicAdd(&cnts[cur], cnt);
            acc = 0.f; cnt = 0.f; cur = b;
        }
        float v = C[(size_t)n * HID + f];
        acc += v > 0.f ? v : 0.f;
        cnt += 1.f;
    }
    atomicAdd(&sums[cur * HID + f], acc);
    if (f == 0) atomicAdd(&cnts[cur], cnt);
}

__global__ __launch_bounds__(256) void mlp_kernel(
    const float* __restrict__ sums, const float* __restrict__ cnts,
    const float* __restrict__ W1, const float* __restrict__ b1,
    const float* __restrict__ W2, const float* __restrict__ b2,
    const float* __restrict__ W3, const float* __restrict__ b3,
    float* __restrict__ out)
{
    __shared__ float sW1[32 * 32], sb1[32], sW2[32 * 16], sb2[16], sW3[16], sb3;
    int tid = threadIdx.x;
    for (int i = tid; i < 32 * 32; i += 256) sW1[i] = W1[i];
    for (int i = tid; i < 32 * 16; i += 256) sW2[i] = W2[i];
    if (tid < 32) sb1[tid] = b1[tid];
    if (tid < 16) { sb2[tid] = b2[tid]; sW3[tid] = W3[tid]; }
    if (tid == 0) sb3 = b3[0];
    __syncthreads();
    int gi = tid;
    float c = cnts[gi]; c = c > 1.f ? c : 1.f;
    float inv = 1.f / c;
    float gvec[32];
    #pragma unroll
    for (int i = 0; i < 32; ++i) gvec[i] = sums[gi * 32 + i] * inv;
    float h1[32];
    #pragma unroll
    for (int j = 0; j < 32; ++j) {
        float a = sb1[j];
        #pragma unroll
        for (int k = 0; k < 32; ++k) a = fmaf(gvec[k], sW1[k * 32 + j], a);
        h1[j] = a > 0.f ? a : 0.f;
    }
    float o = sb3;
    #pragma unroll
    for (int j = 0; j < 16; ++j) {
        float a = sb2[j];
        #pragma unroll
        for (int k = 0; k < 32; ++k) a = fmaf(h1[k], sW2[k * 16 + j], a);
        a = a > 0.f ? a : 0.f;
        o = fmaf(a, sW3[j], o);
    }
    out[gi] = o;
}

extern "C" void kernel_launch(void* const* d_in, const int* in_sizes, int n_in,
                              void* d_out, int out_size, void* d_ws, size_t ws_size,
                              hipStream_t stream) {
    const float* x     = (const float*)d_in[0];
    const int*   ei    = (const int*)d_in[1];
    const float* ew    = (const float*)d_in[2];
    const int*   batch = (const int*)d_in[3];
    const float* c1rw  = (const float*)d_in[4];
    const float* c1rb  = (const float*)d_in[5];
    const float* c1ow  = (const float*)d_in[6];
    const float* c2rw  = (const float*)d_in[7];
    const float* c2rb  = (const float*)d_in[8];
    const float* c2ow  = (const float*)d_in[9];
    const float* l1w   = (const float*)d_in[10];
    const float* l1b   = (const float*)d_in[11];
    const float* l2w   = (const float*)d_in[12];
    const float* l2b   = (const float*)d_in[13];
    const float* lw    = (const float*)d_in[14];
    const float* lb    = (const float*)d_in[15];

    int N = in_sizes[0] / FIN;      // 100000
    int E = in_sizes[2];            // 1600000
    const int* src = ei;
    const int* dst = ei + E;
    int K    = (N + NB_NODES - 1) >> NB_SHIFT;   // 782 buckets
    int NBLK = (E + EPB - 1) / EPB;              // 782 edge blocks

    // ---- workspace layout (with aliasing; ~40 MB total) ----
    char* ws = (char*)d_ws;
    size_t off = 0;
    auto alloc = [&](size_t nbytes) { void* p = ws + off; off += (nbytes + 255) & ~size_t(255); return p; };
    float* A      = (float*)alloc((size_t)N * HID * 4);    // 12.8 MB
    float* BC     = (float*)alloc((size_t)N * HID * 4);    // 12.8 MB
    int2*  perm   = (int2*) alloc((size_t)E * 8);          // 12.8 MB
    int*   rowptr = (int*)  alloc((size_t)(N + 1) * 4);
    int*   btot   = (int*)  alloc((size_t)KMAX * 4);
    int*   bbase  = (int*)  alloc((size_t)(KMAX + 1) * 4);
    float* sums   = (float*)alloc(NGRAPH * HID * 4);       // 32768 B (256-aligned)
    float* cnts   = (float*)alloc(NGRAPH * 4);
    // aliases (dead before the node GEMMs write A/BC):
    int*   stgd   = (int*)A;                               // E*4 = 6.4 MB
    int*   cbb    = (int*)A + E;                           // K*NBLK*4 = 2.45 MB
    int2*  stg8   = (int2*)BC;                             // E*8 = 12.8 MB

    hipMemsetAsync(sums, 0, (NGRAPH * HID + NGRAPH) * 4, stream);

    int nb_node = (N + 7) / 8;
    int nb_agg  = (int)(((long long)N * 64 + 255) / 256);

    // partition build (no global atomics anywhere)
    bucket_hist<<<NBLK, 256, 0, stream>>>(dst, cbb, E, K, NBLK);
    bucket_scan<<<K, 256, 0, stream>>>(cbb, btot, NBLK);
    btot_scan<<<1, 256, 0, stream>>>(btot, bbase, K);
    partB<<<NBLK, 256, 0, stream>>>(src, dst, ew, cbb, bbase, stg8, stgd, E, K, NBLK);
    partC2<<<K, 256, 0, stream>>>(stg8, stgd, bbase, rowptr, perm, N, K);

    // conv1
    node_lin64<<<nb_node, 256, 0, stream>>>(x, c1rw, c1ow, c1rb, A, BC, N);
    csr_agg<<<nb_agg, 256, 0, stream>>>(rowptr, perm, A, BC, N);
    // conv2 (relu fused into node_lin32 load)
    node_lin32<<<nb_node, 256, 0, stream>>>(BC, c2rw, c2ow, c2rb, A, BC, N);
    csr_agg<<<nb_agg, 256, 0, stream>>>(rowptr, perm, A, BC, N);
    // pool + MLP
    pool_kernel<<<(N + 255) / 256, 256, 0, stream>>>(BC, batch, sums, cnts, N);
    mlp_kernel<<<1, 256, 0, stream>>>(sums, cnts, l1w, l1b, l2w, l2b, lw, lb,
                                      (float*)d_out);
}

// Round 6
// 254.874 us; speedup vs baseline: 3.2190x; 1.1138x over previous
//
#include <hip/hip_runtime.h>

#define NGRAPH 256
#define FIN 64
#define HID 32
#define NB_SHIFT 7            // 128 nodes per bucket
#define NB_NODES 128
#define KMAX 1024
#define EPB 4096              // edges per partition block
#define EPT 8                 // edges per thread (512 threads)

// ---------- node GEMMs ----------
__global__ __launch_bounds__(256) void node_lin64(
    const float* __restrict__ x, const float* __restrict__ Wrel,
    const float* __restrict__ Wroot, const float* __restrict__ bias,
    float* __restrict__ A, float* __restrict__ B, int N)
{
    __shared__ float sWr[FIN * HID];
    __shared__ float sWo[FIN * HID];
    __shared__ float sb[HID];
    __shared__ float sx[8 * FIN];
    int tid = threadIdx.x;
    for (int i = tid; i < FIN * HID; i += 256) { sWr[i] = Wrel[i]; sWo[i] = Wroot[i]; }
    if (tid < HID) sb[tid] = bias[tid];
    int base = blockIdx.x * 8;
    for (int i = tid; i < 8 * FIN; i += 256) {
        int n = base + i / FIN;
        sx[i] = (n < N) ? x[(size_t)n * FIN + (i % FIN)] : 0.f;
    }
    __syncthreads();
    int nl = tid >> 5, f = tid & 31, n = base + nl;
    if (n >= N) return;
    float ar = 0.f, ao = 0.f;
    #pragma unroll
    for (int k = 0; k < FIN; ++k) {
        float xv = sx[nl * FIN + k];
        ar = fmaf(xv, sWr[k * HID + f], ar);
        ao = fmaf(xv, sWo[k * HID + f], ao);
    }
    A[(size_t)n * HID + f] = ar;
    B[(size_t)n * HID + f] = ao + sb[f];
}

__global__ __launch_bounds__(256) void node_lin32(
    const float* __restrict__ Hpre, const float* __restrict__ Wrel,
    const float* __restrict__ Wroot, const float* __restrict__ bias,
    float* __restrict__ A, float* __restrict__ C, int N)
{
    __shared__ float sWr[HID * HID];
    __shared__ float sWo[HID * HID];
    __shared__ float sb[HID];
    __shared__ float sh[8 * HID];
    int tid = threadIdx.x;
    for (int i = tid; i < HID * HID; i += 256) { sWr[i] = Wrel[i]; sWo[i] = Wroot[i]; }
    if (tid < HID) sb[tid] = bias[tid];
    int base = blockIdx.x * 8;
    for (int i = tid; i < 8 * HID; i += 256) {
        int n = base + i / HID;
        float v = (n < N) ? Hpre[(size_t)n * HID + (i % HID)] : 0.f;
        sh[i] = v > 0.f ? v : 0.f;
    }
    __syncthreads();
    int nl = tid >> 5, f = tid & 31, n = base + nl;
    if (n >= N) return;
    float ar = 0.f, ao = 0.f;
    #pragma unroll
    for (int k = 0; k < HID; ++k) {
        float hv = sh[nl * HID + k];
        ar = fmaf(hv, sWr[k * HID + f], ar);
        ao = fmaf(hv, sWo[k * HID + f], ao);
    }
    A[(size_t)n * HID + f] = ar;
    C[(size_t)n * HID + f] = ao + sb[f];
}

// ---------- deterministic two-level partition build (no global atomics) ----------

// per-(edge-block, bucket) histogram via LDS; write column blk of cbb
__global__ __launch_bounds__(512) void bucket_hist(
    const int* __restrict__ dst, int* __restrict__ cbb, int E, int K, int NBLK)
{
    __shared__ int h[KMAX];
    int tid = threadIdx.x;
    for (int i = tid; i < K; i += 512) h[i] = 0;
    __syncthreads();
    int e0 = blockIdx.x * EPB + tid * 8;
    if (e0 + 7 < E) {
        int4 d0 = *reinterpret_cast<const int4*>(dst + e0);
        int4 d1 = *reinterpret_cast<const int4*>(dst + e0 + 4);
        atomicAdd(&h[d0.x >> NB_SHIFT], 1); atomicAdd(&h[d0.y >> NB_SHIFT], 1);
        atomicAdd(&h[d0.z >> NB_SHIFT], 1); atomicAdd(&h[d0.w >> NB_SHIFT], 1);
        atomicAdd(&h[d1.x >> NB_SHIFT], 1); atomicAdd(&h[d1.y >> NB_SHIFT], 1);
        atomicAdd(&h[d1.z >> NB_SHIFT], 1); atomicAdd(&h[d1.w >> NB_SHIFT], 1);
    } else {
        for (int e = e0; e < E && e < e0 + 8; ++e)
            atomicAdd(&h[dst[e] >> NB_SHIFT], 1);
    }
    __syncthreads();
    for (int i = tid; i < K; i += 512)
        cbb[(size_t)i * NBLK + blockIdx.x] = h[i];
}

// in-place exclusive scan of each bucket row of cbb; bucket total -> btot
__global__ __launch_bounds__(256) void bucket_scan(
    int* __restrict__ cbb, int* __restrict__ btot, int NBLK)
{
    __shared__ int sc[256];
    size_t row = (size_t)blockIdx.x * NBLK;
    int t = threadIdx.x;
    int base = t * 4;
    int v[4]; int s = 0;
    #pragma unroll
    for (int j = 0; j < 4; ++j) { v[j] = (base + j < NBLK) ? cbb[row + base + j] : 0; s += v[j]; }
    sc[t] = s;
    __syncthreads();
    int acc = s;
    for (int off = 1; off < 256; off <<= 1) {
        int add = (t >= off) ? sc[t - off] : 0;
        __syncthreads();
        acc += add;
        sc[t] = acc;
        __syncthreads();
    }
    int run = acc - s;
    #pragma unroll
    for (int j = 0; j < 4; ++j) {
        if (base + j < NBLK) cbb[row + base + j] = run;
        run += v[j];
    }
    if (t == 255) btot[blockIdx.x] = acc;
}

// single-block exclusive scan of bucket totals -> bbase[0..K], bbase[K]=E
__global__ __launch_bounds__(256) void btot_scan(
    const int* __restrict__ btot, int* __restrict__ bbase, int K)
{
    __shared__ int sc[256];
    int t = threadIdx.x;
    int base = t * 4;
    int v[4]; int s = 0;
    #pragma unroll
    for (int j = 0; j < 4; ++j) { v[j] = (base + j < K) ? btot[base + j] : 0; s += v[j]; }
    sc[t] = s;
    __syncthreads();
    int acc = s;
    for (int off = 1; off < 256; off <<= 1) {
        int add = (t >= off) ? sc[t - off] : 0;
        __syncthreads();
        acc += add;
        sc[t] = acc;
        __syncthreads();
    }
    int run = acc - s;
    #pragma unroll
    for (int j = 0; j < 4; ++j) {
        if (base + j < K) bbase[base + j] = run;
        run += v[j];
    }
    if (t == 255) bbase[K] = acc;
}

// partition: edges -> bucket-grouped staging, offsets fully precomputed
__global__ __launch_bounds__(512) void partB(
    const int* __restrict__ src, const int* __restrict__ dst,
    const float* __restrict__ ew, const int* __restrict__ cbb,
    const int* __restrict__ bbase, int2* __restrict__ stg8,
    int* __restrict__ stgd, int E, int K, int NBLK)
{
    __shared__ int4 pay[EPB];       // 64 KB
    __shared__ int h[KMAX];         // hist, then LDS cursor
    __shared__ int lofs[KMAX];
    __shared__ int gb[KMAX];
    __shared__ int sc[512];
    int tid = threadIdx.x;
    for (int i = tid; i < K; i += 512) h[i] = 0;
    __syncthreads();

    int base = blockIdx.x * EPB;
    int es[EPT], ds[EPT]; float wsr[EPT];
    #pragma unroll
    for (int k = 0; k < EPT; ++k) {
        int e = base + k * 512 + tid;
        if (e < E) {
            es[k] = src[e]; ds[k] = dst[e]; wsr[k] = ew[e];
            atomicAdd(&h[ds[k] >> NB_SHIFT], 1);
        } else ds[k] = -1;
    }
    __syncthreads();

    // block-scan hist over K buckets (thread t owns buckets {2t, 2t+1})
    int b0 = tid * 2;
    int v[2], s = 0;
    #pragma unroll
    for (int j = 0; j < 2; ++j) { int b = b0 + j; v[j] = (b < K) ? h[b] : 0; s += v[j]; }
    sc[tid] = s;
    __syncthreads();
    int acc = s;
    for (int off = 1; off < 512; off <<= 1) {
        int add = (tid >= off) ? sc[tid - off] : 0;
        __syncthreads();
        acc += add;
        sc[tid] = acc;
        __syncthreads();
    }
    int run = acc - s;
    #pragma unroll
    for (int j = 0; j < 2; ++j) {
        int b = b0 + j;
        if (b < K) lofs[b] = run;
        run += v[j];
    }
    __syncthreads();

    // deterministic global bases; convert h[] into LDS scatter cursors
    for (int b = tid; b < K; b += 512) {
        gb[b] = bbase[b] + cbb[(size_t)b * NBLK + blockIdx.x];
        h[b] = lofs[b];
    }
    __syncthreads();

    #pragma unroll
    for (int k = 0; k < EPT; ++k) {
        if (ds[k] >= 0) {
            int b = ds[k] >> NB_SHIFT;
            int slot = atomicAdd(&h[b], 1);
            pay[slot] = make_int4(es[k], __float_as_int(wsr[k]), ds[k],
                                  gb[b] + slot - lofs[b]);
        }
    }
    __syncthreads();

    int tot = E - base; if (tot > EPB) tot = EPB;
    for (int i = tid; i < tot; i += 512) {
        int4 p = pay[i];
        stg8[p.w] = make_int2(p.x, p.y);
        stgd[p.w] = p.z;
    }
}

// per bucket: counting-sort edges by dst node in LDS (parallel scan),
// emit rowptr + node-sorted perm
__global__ __launch_bounds__(256) void partC2(
    const int2* __restrict__ stg8, const int* __restrict__ stgd,
    const int* __restrict__ bbase, int* __restrict__ rowptr,
    int2* __restrict__ perm, int N, int K)
{
    __shared__ int hcnt[NB_NODES];
    __shared__ int hinc[NB_NODES];
    int b = blockIdx.x;
    int n0 = b << NB_SHIFT;
    int nTop = n0 + NB_NODES; if (nTop > N) nTop = N;
    int nloc = nTop - n0;
    int tid = threadIdx.x;
    if (tid < NB_NODES) hcnt[tid] = 0;
    __syncthreads();
    int lo = bbase[b], hi = bbase[b + 1];
    for (int e = lo + tid; e < hi; e += 256)
        atomicAdd(&hcnt[stgd[e] - n0], 1);
    __syncthreads();
    if (tid < NB_NODES) hinc[tid] = hcnt[tid];
    __syncthreads();
    // parallel inclusive scan over 128 counters
    for (int off = 1; off < NB_NODES; off <<= 1) {
        int v = (tid < NB_NODES && tid >= off) ? hinc[tid - off] : 0;
        __syncthreads();
        if (tid < NB_NODES) hinc[tid] += v;
        __syncthreads();
    }
    if (tid < nloc) {
        int excl = hinc[tid] - hcnt[tid];
        rowptr[n0 + tid] = lo + excl;
        hcnt[tid] = excl;               // reuse as cursor
    }
    if (b == K - 1 && tid == 0) rowptr[N] = hi;
    __syncthreads();
    for (int e = lo + tid; e < hi; e += 256) {
        int2 p = stg8[e];
        int pos = lo + atomicAdd(&hcnt[stgd[e] - n0], 1);
        perm[pos] = p;
    }
}

// ---------- gather-side aggregation ----------
// 64 lanes per node (2 halves x 32 features), 4 accumulators per half:
// 8 independent A-row gathers in flight per wave
__global__ __launch_bounds__(256) void csr_agg(
    const int* __restrict__ rowptr, const int2* __restrict__ perm,
    const float* __restrict__ A, float* __restrict__ out, int N)
{
    int gid = blockIdx.x * 256 + threadIdx.x;
    int n = gid >> 6;
    if (n >= N) return;
    int half = (threadIdx.x >> 5) & 1;
    int f = threadIdx.x & 31;
    int e0 = rowptr[n], e1 = rowptr[n + 1];
    float a0 = 0.f, a1 = 0.f, a2 = 0.f, a3 = 0.f;
    int e = e0 + half;
    for (; e + 6 < e1; e += 8) {
        int2 p0 = perm[e];
        int2 p1 = perm[e + 2];
        int2 p2 = perm[e + 4];
        int2 p3 = perm[e + 6];
        a0 = fmaf(A[((size_t)p0.x << 5) + f], __int_as_float(p0.y), a0);
        a1 = fmaf(A[((size_t)p1.x << 5) + f], __int_as_float(p1.y), a1);
        a2 = fmaf(A[((size_t)p2.x << 5) + f], __int_as_float(p2.y), a2);
        a3 = fmaf(A[((size_t)p3.x << 5) + f], __int_as_float(p3.y), a3);
    }
    for (; e < e1; e += 2) {
        int2 p = perm[e];
        a0 = fmaf(A[((size_t)p.x << 5) + f], __int_as_float(p.y), a0);
    }
    float acc = (a0 + a1) + (a2 + a3);
    acc += __shfl_xor(acc, 32, 64);
    if (half == 0) out[((size_t)n << 5) + f] += acc;
}

// ---------- pool + MLP ----------
__global__ __launch_bounds__(256) void pool_kernel(
    const float* __restrict__ C, const int* __restrict__ batch,
    float* __restrict__ sums, float* __restrict__ cnts, int N)
{
    int f = threadIdx.x & 31, g = threadIdx.x >> 5;
    int n0 = blockIdx.x * 256 + g * 32;
    if (n0 >= N) return;
    int n1 = n0 + 32; if (n1 > N) n1 = N;
    int cur = batch[n0];
    float acc = 0.f, cnt = 0.f;
    for (int n = n0; n < n1; ++n) {
        int b = batch[n];
        if (b != cur) {
            atomicAdd(&sums[cur * HID + f], acc);
            if (f == 0) atomicAdd(&cnts[cur], cnt);
            acc = 0.f; cnt = 0.f; cur = b;
        }
        float v = C[(size_t)n * HID + f];
        acc += v > 0.f ? v : 0.f;
        cnt += 1.f;
    }
    atomicAdd(&sums[cur * HID + f], acc);
    if (f == 0) atomicAdd(&cnts[cur], cnt);
}

__global__ __launch_bounds__(256) void mlp_kernel(
    const float* __restrict__ sums, const float* __restrict__ cnts,
    const float* __restrict__ W1, const float* __restrict__ b1,
    const float* __restrict__ W2, const float* __restrict__ b2,
    const float* __restrict__ W3, const float* __restrict__ b3,
    float* __restrict__ out)
{
    __shared__ float sW1[32 * 32], sb1[32], sW2[32 * 16], sb2[16], sW3[16], sb3;
    int tid = threadIdx.x;
    for (int i = tid; i < 32 * 32; i += 256) sW1[i] = W1[i];
    for (int i = tid; i < 32 * 16; i += 256) sW2[i] = W2[i];
    if (tid < 32) sb1[tid] = b1[tid];
    if (tid < 16) { sb2[tid] = b2[tid]; sW3[tid] = W3[tid]; }
    if (tid == 0) sb3 = b3[0];
    __syncthreads();
    int gi = tid;
    float c = cnts[gi]; c = c > 1.f ? c : 1.f;
    float inv = 1.f / c;
    float gvec[32];
    #pragma unroll
    for (int i = 0; i < 32; ++i) gvec[i] = sums[gi * 32 + i] * inv;
    float h1[32];
    #pragma unroll
    for (int j = 0; j < 32; ++j) {
        float a = sb1[j];
        #pragma unroll
        for (int k = 0; k < 32; ++k) a = fmaf(gvec[k], sW1[k * 32 + j], a);
        h1[j] = a > 0.f ? a : 0.f;
    }
    float o = sb3;
    #pragma unroll
    for (int j = 0; j < 16; ++j) {
        float a = sb2[j];
        #pragma unroll
        for (int k = 0; k < 32; ++k) a = fmaf(h1[k], sW2[k * 16 + j], a);
        a = a > 0.f ? a : 0.f;
        o = fmaf(a, sW3[j], o);
    }
    out[gi] = o;
}

extern "C" void kernel_launch(void* const* d_in, const int* in_sizes, int n_in,
                              void* d_out, int out_size, void* d_ws, size_t ws_size,
                              hipStream_t stream) {
    const float* x     = (const float*)d_in[0];
    const int*   ei    = (const int*)d_in[1];
    const float* ew    = (const float*)d_in[2];
    const int*   batch = (const int*)d_in[3];
    const float* c1rw  = (const float*)d_in[4];
    const float* c1rb  = (const float*)d_in[5];
    const float* c1ow  = (const float*)d_in[6];
    const float* c2rw  = (const float*)d_in[7];
    const float* c2rb  = (const float*)d_in[8];
    const float* c2ow  = (const float*)d_in[9];
    const float* l1w   = (const float*)d_in[10];
    const float* l1b   = (const float*)d_in[11];
    const float* l2w   = (const float*)d_in[12];
    const float* l2b   = (const float*)d_in[13];
    const float* lw    = (const float*)d_in[14];
    const float* lb    = (const float*)d_in[15];

    int N = in_sizes[0] / FIN;      // 100000
    int E = in_sizes[2];            // 1600000
    const int* src = ei;
    const int* dst = ei + E;
    int K    = (N + NB_NODES - 1) >> NB_SHIFT;   // 782 buckets
    int NBLK = (E + EPB - 1) / EPB;              // 391 edge blocks

    // ---- workspace layout (with aliasing; ~40 MB total) ----
    char* ws = (char*)d_ws;
    size_t off = 0;
    auto alloc = [&](size_t nbytes) { void* p = ws + off; off += (nbytes + 255) & ~size_t(255); return p; };
    float* A      = (float*)alloc((size_t)N * HID * 4);    // 12.8 MB
    float* BC     = (float*)alloc((size_t)N * HID * 4);    // 12.8 MB
    int2*  perm   = (int2*) alloc((size_t)E * 8);          // 12.8 MB
    int*   rowptr = (int*)  alloc((size_t)(N + 1) * 4);
    int*   btot   = (int*)  alloc((size_t)KMAX * 4);
    int*   bbase  = (int*)  alloc((size_t)(KMAX + 1) * 4);
    float* sums   = (float*)alloc(NGRAPH * HID * 4);
    float* cnts   = (float*)alloc(NGRAPH * 4);
    // aliases (dead before the node GEMMs write A/BC):
    int*   stgd   = (int*)A;                               // E*4 = 6.4 MB
    int*   cbb    = (int*)A + E;                           // K*NBLK*4 = 1.2 MB
    int2*  stg8   = (int2*)BC;                             // E*8 = 12.8 MB

    hipMemsetAsync(sums, 0, (NGRAPH * HID + NGRAPH) * 4, stream);

    int nb_node = (N + 7) / 8;
    int nb_agg  = (int)(((long long)N * 64 + 255) / 256);

    // partition build (no global atomics anywhere)
    bucket_hist<<<NBLK, 512, 0, stream>>>(dst, cbb, E, K, NBLK);
    bucket_scan<<<K, 256, 0, stream>>>(cbb, btot, NBLK);
    btot_scan<<<1, 256, 0, stream>>>(btot, bbase, K);
    partB<<<NBLK, 512, 0, stream>>>(src, dst, ew, cbb, bbase, stg8, stgd, E, K, NBLK);
    partC2<<<K, 256, 0, stream>>>(stg8, stgd, bbase, rowptr, perm, N, K);

    // conv1
    node_lin64<<<nb_node, 256, 0, stream>>>(x, c1rw, c1ow, c1rb, A, BC, N);
    csr_agg<<<nb_agg, 256, 0, stream>>>(rowptr, perm, A, BC, N);
    // conv2 (relu fused into node_lin32 load)
    node_lin32<<<nb_node, 256, 0, stream>>>(BC, c2rw, c2ow, c2rb, A, BC, N);
    csr_agg<<<nb_agg, 256, 0, stream>>>(rowptr, perm, A, BC, N);
    // pool + MLP
    pool_kernel<<<(N + 255) / 256, 256, 0, stream>>>(BC, batch, sums, cnts, N);
    mlp_kernel<<<1, 256, 0, stream>>>(sums, cnts, l1w, l1b, l2w, l2b, lw, lb,
                                      (float*)d_out);
}